// Round 9
// baseline (266.608 us; speedup 1.0000x reference)
//
#include <hip/hip_runtime.h>
#include <math.h>

// Problem constants (fixed by setup_inputs)
#define QTOT   8192
#define LNUM   4
#define PNUM   4
#define NHEAD  8
#define DHEAD  32
#define HMAX   128
#define NV_PER_B 21760           // 128^2 + 64^2 + 32^2 + 16^2
#define MROWS  (2 * NV_PER_B)    // 43520 valid value rows
#define QPERB  4096              // batch_offsets = [0, 4096]

// grouped-GEMM grid split
#define G1_MT  (MROWS / 128)     // 340 m-tiles for vproj GEMM
#define G1_BLKS (G1_MT * 2)      // 680 (N=256 -> 2 n-tiles)
#define G2_BLKS (128 * 3)        // 384 (M=8192/64, N=384 -> 3 n-tiles)

typedef __attribute__((ext_vector_type(8))) short bf16x8;
typedef __attribute__((ext_vector_type(4))) float f32x4;

static __device__ __forceinline__ ushort bf16_hi(float f) {
    return (ushort)(__builtin_bit_cast(unsigned int, f) >> 16);
}
static __device__ __forceinline__ ushort bf16_lo(float f, ushort hi) {
    float hf = __builtin_bit_cast(float, ((unsigned int)hi) << 16);
    return (ushort)(__builtin_bit_cast(unsigned int, f - hf) >> 16);
}
static __device__ __forceinline__ ushort bf16_rne(float f) {
    unsigned u = __builtin_bit_cast(unsigned int, f);
    unsigned rr = (u + 0x7FFFu + ((u >> 16) & 1u)) >> 16;
    return (ushort)rr;
}

// ---------------------------------------------------------------------------
// Split-bf16 MFMA NT GEMM body: Out[M][ldo] = A[M][256] * B[N][256]^T + bias
// NPROD=3: a*b ~= ahi*bhi + ahi*blo + alo*bhi; NPROD=1: plain bf16.
// OUTBF16: store bf16 (RNE). GATHER: A rows from sparse values tensor.
// BMx128 tile, BK=32, 256 threads = 4 waves (2x2), 16x16x32 MFMA,
// double-buffered LDS with XOR chunk-swizzle. smem is caller-provided.
// LDS bytes needed: (2*PL*BM*32 + 2*PL*128*32)*2 + (GATHER ? 4*BM : 0)
//   mode1 <1,128,1,1>: 16K + 16K + 512 = 32.5 KB
//   mode2 <0, 64,3,0>: 16K + 32K       = 48 KB   <-- max
//   out   <0, 64,1,0>:  8K + 16K       = 24 KB
// ---------------------------------------------------------------------------
template<int GATHER, int BM, int NPROD, int OUTBF16>
__device__ __forceinline__
void gemm_body(const float* __restrict__ A,
               const float* __restrict__ B1,
               const float* __restrict__ B2,
               const float* __restrict__ bias1,
               const float* __restrict__ bias2,
               void* __restrict__ Out,
               int nsplit, int ldo, int bx, int by, char* smem)
{
    constexpr int MI  = BM / 32;          // m-frags per wave
    constexpr int AIT = BM * 8 / 256;     // float4 staging slots per thread (A)
    constexpr int PL  = (NPROD > 1) ? 2 : 1;   // LDS planes (hi[,lo])
    ushort* sAp = (ushort*)smem;                    // [2][PL][BM*32]
    ushort* sBp = sAp + 2 * PL * BM * 32;           // [2][PL][128*32]
    int* rowBase = (int*)(sBp + 2 * PL * 128 * 32); // [BM] (GATHER only)

    const int tid = threadIdx.x;
    const int m0 = bx * BM;
    const int n0 = by * 128;

    if (GATHER) {
        for (int s = tid; s < BM; s += 256) {
            int r = m0 + s;
            int b = (r >= NV_PER_B) ? 1 : 0;
            int rp = r - b * NV_PER_B;
            int l, y, x;
            if (rp < 16384)      { l = 0; y = rp >> 7; x = rp & 127; }
            else if (rp < 20480) { int rr = rp - 16384; l = 1; y = rr >> 6; x = rr & 63; }
            else if (rp < 21504) { int rr = rp - 20480; l = 2; y = rr >> 5; x = rr & 31; }
            else                 { int rr = rp - 21504; l = 3; y = rr >> 4; x = rr & 15; }
            rowBase[s] = (((((b << 7) | y) << 7) | x) * 4 + l) << 8;
        }
        __syncthreads();
    }

    float4 pa[AIT], pb[4];

    auto loadA = [&](int kt) {
        #pragma unroll
        for (int i = 0; i < AIT; ++i) {
            int s = tid + i * 256;
            int r = s >> 3, c4 = s & 7;
            const float* src = GATHER
                ? A + rowBase[r] + kt * 32 + c4 * 4
                : A + (size_t)(m0 + r) * 256 + kt * 32 + c4 * 4;
            pa[i] = *(const float4*)src;
        }
        #pragma unroll
        for (int i = 0; i < 4; ++i) {
            int s = tid + i * 256;
            int r = s >> 3, c4 = s & 7;
            int bn = n0 + r;
            const float* src = ((bn < nsplit) ? B1 + (size_t)bn * 256
                                              : B2 + (size_t)(bn - nsplit) * 256)
                               + kt * 32 + c4 * 4;
            pb[i] = *(const float4*)src;
        }
    };

    auto writeLDS = [&](int buf) {
        #pragma unroll
        for (int i = 0; i < AIT; ++i) {
            int s = tid + i * 256;
            int r = s >> 3, c4 = s & 7;
            float4 v = pa[i];
            ushort4 hi;
            hi.x = bf16_hi(v.x); hi.y = bf16_hi(v.y);
            hi.z = bf16_hi(v.z); hi.w = bf16_hi(v.w);
            int idx = r * 32 + ((((c4 >> 1) ^ (r & 3)) << 3) | ((c4 & 1) << 2));
            *(ushort4*)&sAp[(buf * PL + 0) * BM * 32 + idx] = hi;
            if (NPROD > 1) {
                ushort4 lo;
                lo.x = bf16_lo(v.x, hi.x); lo.y = bf16_lo(v.y, hi.y);
                lo.z = bf16_lo(v.z, hi.z); lo.w = bf16_lo(v.w, hi.w);
                *(ushort4*)&sAp[(buf * PL + PL - 1) * BM * 32 + idx] = lo;
            }
        }
        #pragma unroll
        for (int i = 0; i < 4; ++i) {
            int s = tid + i * 256;
            int r = s >> 3, c4 = s & 7;
            float4 v = pb[i];
            ushort4 hi;
            hi.x = bf16_hi(v.x); hi.y = bf16_hi(v.y);
            hi.z = bf16_hi(v.z); hi.w = bf16_hi(v.w);
            int idx = r * 32 + ((((c4 >> 1) ^ (r & 3)) << 3) | ((c4 & 1) << 2));
            *(ushort4*)&sBp[(buf * PL + 0) * 128 * 32 + idx] = hi;
            if (NPROD > 1) {
                ushort4 lo;
                lo.x = bf16_lo(v.x, hi.x); lo.y = bf16_lo(v.y, hi.y);
                lo.z = bf16_lo(v.z, hi.z); lo.w = bf16_lo(v.w, hi.w);
                *(ushort4*)&sBp[(buf * PL + PL - 1) * 128 * 32 + idx] = lo;
            }
        }
    };

    const int lane = tid & 63;
    const int wid  = tid >> 6;
    const int wrow = (wid >> 1) * (BM / 2);
    const int wcol = (wid & 1) * 64;
    const int fr   = lane & 15;
    const int ks   = lane >> 4;

    f32x4 acc[MI][4] = {};

    loadA(0);
    writeLDS(0);

    for (int kt = 0; kt < 8; ++kt) {
        __syncthreads();
        if (kt < 7) loadA(kt + 1);

        const int buf = kt & 1;
        bf16x8 ah[MI], al[MI], bh[4], bl[4];
        #pragma unroll
        for (int mi = 0; mi < MI; ++mi) {
            int row = wrow + mi * 16 + fr;
            int idx = row * 32 + ((ks ^ (row & 3)) << 3);
            ah[mi] = *(const bf16x8*)&sAp[(buf * PL + 0) * BM * 32 + idx];
            if (NPROD > 1) al[mi] = *(const bf16x8*)&sAp[(buf * PL + PL - 1) * BM * 32 + idx];
        }
        #pragma unroll
        for (int ni = 0; ni < 4; ++ni) {
            int row = wcol + ni * 16 + fr;
            int idx = row * 32 + ((ks ^ (row & 3)) << 3);
            bh[ni] = *(const bf16x8*)&sBp[(buf * PL + 0) * 128 * 32 + idx];
            if (NPROD > 1) bl[ni] = *(const bf16x8*)&sBp[(buf * PL + PL - 1) * 128 * 32 + idx];
        }
        #pragma unroll
        for (int mi = 0; mi < MI; ++mi)
            #pragma unroll
            for (int ni = 0; ni < 4; ++ni) {
                acc[mi][ni] = __builtin_amdgcn_mfma_f32_16x16x32_bf16(ah[mi], bh[ni], acc[mi][ni], 0, 0, 0);
                if (NPROD > 1) {
                    acc[mi][ni] = __builtin_amdgcn_mfma_f32_16x16x32_bf16(ah[mi], bl[ni], acc[mi][ni], 0, 0, 0);
                    acc[mi][ni] = __builtin_amdgcn_mfma_f32_16x16x32_bf16(al[mi], bh[ni], acc[mi][ni], 0, 0, 0);
                }
            }

        if (kt < 7) writeLDS((kt + 1) & 1);
    }

    // epilogue: D[row=(lane>>4)*4+r][col=lane&15] per 16x16 frag
    #pragma unroll
    for (int mi = 0; mi < MI; ++mi)
        #pragma unroll
        for (int ni = 0; ni < 4; ++ni) {
            int col = n0 + wcol + ni * 16 + fr;
            float bs = (col < nsplit) ? bias1[col] : bias2[col - nsplit];
            int rbase = m0 + wrow + mi * 16 + ks * 4;
            #pragma unroll
            for (int rr = 0; rr < 4; ++rr) {
                float val = acc[mi][ni][rr] + bs;
                if (OUTBF16)
                    ((ushort*)Out)[(size_t)(rbase + rr) * ldo + col] = bf16_rne(val);
                else
                    ((float*)Out)[(size_t)(rbase + rr) * ldo + col] = val;
            }
        }
}

// ---------------------------------------------------------------------------
// Grouped launch: GEMM1 (vproj) and GEMM2 (qbuf) are independent — run them
// as one grid so their work fills the machine concurrently.
// blocks [0, 680): mode 1 — vproj = bf16(values_valid @ W_v^T + b_v)
// blocks [680, 1064): mode 2 — qbuf = query @ [W_so;W_aw]^T + bias (3-prod)
// ---------------------------------------------------------------------------
__global__ __launch_bounds__(256)
void fused_g12(const float* __restrict__ values,
               const float* __restrict__ W_v,  const float* __restrict__ b_v,
               const float* __restrict__ query,
               const float* __restrict__ W_so, const float* __restrict__ W_aw,
               const float* __restrict__ b_so, const float* __restrict__ b_aw,
               ushort* __restrict__ vproj, float* __restrict__ qbuf)
{
    extern __shared__ char smem[];
    const int f = blockIdx.x;
    if (f < G1_BLKS) {
        gemm_body<1, 128, 1, 1>(values, W_v, W_v, b_v, b_v, vproj,
                                256, 256, f % G1_MT, f / G1_MT, smem);
    } else {
        const int g = f - G1_BLKS;
        gemm_body<0, 64, 3, 0>(query, W_so, W_aw, b_so, b_aw, qbuf,
                               256, 384, g % 128, g / 128, smem);
    }
}

// output projection kernel (separate: depends on sample's mid)
__global__ __launch_bounds__(256)
void gemm_o(const float* __restrict__ mid,
            const float* __restrict__ W_o, const float* __restrict__ b_o,
            float* __restrict__ out)
{
    extern __shared__ char smem[];
    gemm_body<0, 64, 1, 0>(mid, W_o, W_o, b_o, b_o, out,
                           256, 256, blockIdx.x, blockIdx.y, smem);
}

// ---------------------------------------------------------------------------
// Sampling v2: ONE query per block, 256 threads.
// Phase 1 (tid<128): per (l,p,h) combo compute corner rows + weights -> LDS
//   (packed int2 {row, w}), stash attention logits.
// Phase 2 (tid<8): softmax over 16 (l,p) logits per head.
// Phase 2b: fold aw into the 512 corner weights.
// Phase 3: lane = ds(0..3) + 4*rt(0..7) within each head's 32 lanes.
//   Each lane: 8 x 16B uint4 gathers (its rt-th row-task of 64), 8-channel
//   accumulate; 3-step __shfl_xor reduce over rt; lanes rt==0 store.
//   vs v1: 8x parallelism per (q,h), 2x fewer VMEM issues, 8x shorter chains.
// ---------------------------------------------------------------------------
__global__ __launch_bounds__(256)
void sample1(const ushort* __restrict__ vproj,  // [MROWS][256] bf16
             const float* __restrict__ qbuf,    // [Q][384]: 256 offs | 128 aw logits
             const float* __restrict__ ref,     // [Q][2]
             float* __restrict__ mid)           // [Q][256]
{
    __shared__ int2  s_rw[128][4];     // {compact row, weight bits}
    __shared__ float s_logit[16][8];
    __shared__ float s_aw[16][8];

    const int tid = threadIdx.x;
    const int q = blockIdx.x;
    const int b = (q >= QPERB) ? 1 : 0;

    if (tid < 128) {
        const int c  = tid;            // (l*4+p)*8 + h
        const int lp = c >> 3;
        const int l  = lp >> 2;
        const float2 off = *(const float2*)&qbuf[(size_t)q * 384 + c * 2];
        float rx = fminf(fmaxf(ref[q * 2 + 0], 0.f), 1.f);
        float ry = fminf(fmaxf(ref[q * 2 + 1], 0.f), 1.f);
        const float eps = 1e-5f;
        const float isx = logf(fmaxf(rx, eps) / fmaxf(1.f - rx, eps));
        const float isy = logf(fmaxf(ry, eps) / fmaxf(1.f - ry, eps));
        const float locx = 1.f / (1.f + expf(-(isx + off.x)));
        const float locy = 1.f / (1.f + expf(-(isy + off.y)));
        const int Wl = HMAX >> l, Hl = HMAX >> l;
        const float x = locx * (float)Wl - 0.5f;
        const float y = locy * (float)Hl - 0.5f;
        const float x0f = floorf(x), y0f = floorf(y);
        const float wx1 = x - x0f, wx0 = 1.f - wx1;
        const float wy1 = y - y0f, wy0 = 1.f - wy1;
        const int x0 = (int)x0f, y0 = (int)y0f;
        const int lo = (l == 0) ? 0 : (l == 1) ? 16384 : (l == 2) ? 20480 : 21504;
        const int base = b * NV_PER_B + lo;
        const int   xs[2] = {x0, x0 + 1};
        const int   ys[2] = {y0, y0 + 1};
        const float wxs[2] = {wx0, wx1};
        const float wys[2] = {wy0, wy1};
        #pragma unroll
        for (int cy = 0; cy < 2; ++cy)
            #pragma unroll
            for (int cx = 0; cx < 2; ++cx) {
                const int xi = xs[cx], yi = ys[cy];
                const bool valid = (xi >= 0) & (xi < Wl) & (yi >= 0) & (yi < Hl);
                const int idx = cy * 2 + cx;
                s_rw[c][idx].x = valid ? (base + yi * Wl + xi) : 0;
                s_rw[c][idx].y = __float_as_int(valid ? (wys[cy] * wxs[cx]) : 0.f);
            }
        s_logit[lp][c & 7] = qbuf[(size_t)q * 384 + 256 + c];
    }
    __syncthreads();

    if (tid < 8) {
        const int h = tid;
        float m = -INFINITY;
        #pragma unroll
        for (int j = 0; j < 16; ++j) m = fmaxf(m, s_logit[j][h]);
        float s = 0.f;
        #pragma unroll
        for (int j = 0; j < 16; ++j) s += expf(s_logit[j][h] - m);
        const float inv = 1.f / s;
        #pragma unroll
        for (int j = 0; j < 16; ++j)
            s_aw[j][h] = expf(s_logit[j][h] - m) * inv;
    }
    __syncthreads();

    // fold aw into corner weights: 512 (c,j) pairs / 256 threads
    #pragma unroll
    for (int t2 = tid; t2 < 512; t2 += 256) {
        const int c = t2 >> 2, j = t2 & 3;
        const float aw = s_aw[c >> 3][c & 7];
        s_rw[c][j].y = __float_as_int(__int_as_float(s_rw[c][j].y) * aw);
    }
    __syncthreads();

    // phase 3: gather + accumulate + shuffle-reduce
    const int h  = tid >> 5;        // head
    const int l5 = tid & 31;
    const int ds = l5 & 3;          // d-slice (8 channels)
    const int rt = l5 >> 2;         // row-task 0..7
    const int j  = rt & 3;          // corner (it-invariant)
    const int rtH = rt >> 2;        // 0/1

    float a0 = 0.f, a1 = 0.f, a2 = 0.f, a3 = 0.f;
    float a4 = 0.f, a5 = 0.f, a6 = 0.f, a7 = 0.f;
    #pragma unroll
    for (int it = 0; it < 8; ++it) {
        const int lp = 2 * it + rtH;
        const int c = lp * 8 + h;
        const int2 rw = s_rw[c][j];
        const float w = __int_as_float(rw.y);
        const uint4 u = *(const uint4*)&vproj[(size_t)rw.x * 256 + h * 32 + ds * 8];
        a0 = fmaf(w, __builtin_bit_cast(float, u.x << 16), a0);
        a1 = fmaf(w, __builtin_bit_cast(float, u.x & 0xFFFF0000u), a1);
        a2 = fmaf(w, __builtin_bit_cast(float, u.y << 16), a2);
        a3 = fmaf(w, __builtin_bit_cast(float, u.y & 0xFFFF0000u), a3);
        a4 = fmaf(w, __builtin_bit_cast(float, u.z << 16), a4);
        a5 = fmaf(w, __builtin_bit_cast(float, u.z & 0xFFFF0000u), a5);
        a6 = fmaf(w, __builtin_bit_cast(float, u.w << 16), a6);
        a7 = fmaf(w, __builtin_bit_cast(float, u.w & 0xFFFF0000u), a7);
    }
    // reduce over rt (lane bits 2,3,4)
    #pragma unroll
    for (int m = 4; m <= 16; m <<= 1) {
        a0 += __shfl_xor(a0, m); a1 += __shfl_xor(a1, m);
        a2 += __shfl_xor(a2, m); a3 += __shfl_xor(a3, m);
        a4 += __shfl_xor(a4, m); a5 += __shfl_xor(a5, m);
        a6 += __shfl_xor(a6, m); a7 += __shfl_xor(a7, m);
    }
    if (rt == 0) {
        float* dst = &mid[(size_t)q * 256 + h * 32 + ds * 8];
        float4 o0 = {a0, a1, a2, a3};
        float4 o1 = {a4, a5, a6, a7};
        *(float4*)dst = o0;
        *(float4*)(dst + 4) = o1;
    }
}

// ---------------------------------------------------------------------------
extern "C" void kernel_launch(void* const* d_in, const int* in_sizes, int n_in,
                              void* d_out, int out_size, void* d_ws, size_t ws_size,
                              hipStream_t stream)
{
    const float* query  = (const float*)d_in[0];
    const float* ref    = (const float*)d_in[1];
    const float* values = (const float*)d_in[2];
    const float* W_so   = (const float*)d_in[3];
    const float* b_so   = (const float*)d_in[4];
    const float* W_aw   = (const float*)d_in[5];
    const float* b_aw   = (const float*)d_in[6];
    const float* W_v    = (const float*)d_in[7];
    const float* b_v    = (const float*)d_in[8];
    const float* W_o    = (const float*)d_in[9];
    const float* b_o    = (const float*)d_in[10];
    float* out = (float*)d_out;

    ushort* vproj = (ushort*)d_ws;                     // [43520][256] bf16
    float* qbuf  = (float*)d_ws + ((size_t)MROWS * 256 * 2) / 4;  // [8192][384] f32
    float* mid   = qbuf + (size_t)QTOT * 384;          // [8192][256] f32

    // mode-2 needs 48 KB (sA 16K + sB 32K); +1 KB pad for rowBase (mode 1).
    const int smem_bytes = 48 * 1024 + 1024;

    dim3 blk(256);
    // 1+2) grouped: vproj GEMM (680 blocks) ++ query projections (384 blocks)
    fused_g12<<<dim3(G1_BLKS + G2_BLKS), blk, smem_bytes, stream>>>(
        values, W_v, b_v, query, W_so, W_aw, b_so, b_aw, vproj, qbuf);
    // 3) deformable sampling + softmax-weighted head accumulation
    sample1<<<dim3(QTOT), blk, 0, stream>>>(vproj, qbuf, ref, mid);
    // 4) output projection
    gemm_o<<<dim3(QTOT / 64, 2), blk, smem_bytes, stream>>>(mid, W_o, b_o, out);
}